// Round 17
// baseline (48.602 us; speedup 1.0000x reference)
//
#include <hip/hip_runtime.h>

#define SB 32      // batch
#define SS 2048    // sequence
#define SH 2       // heads
#define SD 4       // head dim
#define SE 8       // embed

#define LOG2E 1.44269504f

typedef float    f32x16 __attribute__((ext_vector_type(16)));
typedef _Float16 f16x8  __attribute__((ext_vector_type(8)));

static __device__ __forceinline__ float fast_exp2(float x) {
#if __has_builtin(__builtin_amdgcn_exp2f)
    return __builtin_amdgcn_exp2f(x);
#else
    return exp2f(x);
#endif
}

static __device__ __forceinline__ int cvtpk(float a, float b) {
    auto h = __builtin_amdgcn_cvt_pkrtz(a, b);
    union { decltype(h) hh; int i; } u; u.hh = h; return u.i;
}

// exchange register halves across the lane<32 / lane>=32 boundary
static __device__ __forceinline__ void swap32(int a, int b, int lane, int& r0, int& r1) {
#if __has_builtin(__builtin_amdgcn_permlane32_swap)
    auto r = __builtin_amdgcn_permlane32_swap(a, b, false, false);
    r0 = r[0]; r1 = r[1];
#else
    const int blo = __builtin_amdgcn_ds_bpermute((lane & 31) << 2, b);
    const int ahi = __builtin_amdgcn_ds_bpermute(((lane ^ 32) & 63) << 2, a);
    r0 = (lane < 32) ? a : blo;
    r1 = (lane < 32) ? ahi : b;
#endif
}

static __device__ __forceinline__ f16x8 frag2(unsigned x, unsigned y) {
    union { unsigned u[4]; f16x8 h; } c;
    c.u[0] = x; c.u[1] = y; c.u[2] = 0; c.u[3] = 0; return c.h;
}
static __device__ __forceinline__ f16x8 frag4(uint4 v) {
    union { uint4 u; f16x8 h; } c; c.u = v; return c.h;
}
static __device__ __forceinline__ f16x8 fragi(int a, int b, int c_, int d) {
    union { int u[4]; f16x8 h; } c;
    c.u[0] = a; c.u[1] = b; c.u[2] = c_; c.u[3] = d; return c.h;
}

union u32h2 { unsigned u; _Float16 h[2]; };
static __device__ __forceinline__ unsigned packh2(float a, float b) {
    u32h2 c; c.h[0] = (_Float16)a; c.h[1] = (_Float16)b; return c.u;
}

// ---------------------------------------------------------------------------
// Kernel 1: moving averages + QKV projection (unchanged).
// ---------------------------------------------------------------------------
__global__ __launch_bounds__(256) void k_ma_qkv(
    const float* __restrict__ x,      // [B,S]
    const float* __restrict__ Wq,     // [4,4] row-major W[e*4+d]
    const float* __restrict__ Wk,
    const float* __restrict__ Wv,
    uint2* __restrict__ qws16,        // [B*H*S] packed f16 {q01,q23}
    uint2* __restrict__ kws16,        // [B*H*S]
    _Float16* __restrict__ vtg,       // [B*H][4][S] V transposed, f16
    float4* __restrict__ mmws)        // [B*S*2]
{
    __shared__ float xs[272];

    const int tile = blockIdx.x % (SS / 256);
    const int b    = blockIdx.x / (SS / 256);
    const int s0   = tile * 256;
    const float* xrow = x + b * SS;

    for (int i = threadIdx.x; i < 272; i += 256) {
        int idx = s0 - 8 + i;
        idx = min(max(idx, 0), SS - 1);
        xs[i] = xrow[idx];
    }
    __syncthreads();

    const int t = threadIdx.x;
    const int s = s0 + t;

    float mmv[8];
    float c = xs[8 + t];
    #pragma unroll
    for (int h = 1; h <= 8; ++h) {
        c += xs[8 + t - h] + xs[8 + t + h];
        mmv[h - 1] = c * (1.0f / (float)(2 * h + 1));
    }

    mmws[(b * SS + s) * 2 + 0] = make_float4(mmv[0], mmv[1], mmv[2], mmv[3]);
    mmws[(b * SS + s) * 2 + 1] = make_float4(mmv[4], mmv[5], mmv[6], mmv[7]);

    const float qscale = 0.5f * LOG2E;  // 1/sqrt(D) * log2(e)
    #pragma unroll
    for (int h = 0; h < SH; ++h) {
        const float t0 = mmv[h * 4 + 0];
        const float t1 = mmv[h * 4 + 1];
        const float t2 = mmv[h * 4 + 2];
        const float t3 = mmv[h * 4 + 3];
        float q[4], k[4], v[4];
        #pragma unroll
        for (int e = 0; e < 4; ++e) {
            q[e] = (t0 * Wq[e * 4 + 0] + t1 * Wq[e * 4 + 1] +
                    t2 * Wq[e * 4 + 2] + t3 * Wq[e * 4 + 3]) * qscale;
            k[e] =  t0 * Wk[e * 4 + 0] + t1 * Wk[e * 4 + 1] +
                    t2 * Wk[e * 4 + 2] + t3 * Wk[e * 4 + 3];
            v[e] =  t0 * Wv[e * 4 + 0] + t1 * Wv[e * 4 + 1] +
                    t2 * Wv[e * 4 + 2] + t3 * Wv[e * 4 + 3];
        }
        const int bh  = b * SH + h;
        const int idx = bh * SS + s;
        qws16[idx] = make_uint2(packh2(q[0], q[1]), packh2(q[2], q[3]));
        kws16[idx] = make_uint2(packh2(k[0], k[1]), packh2(k[2], k[3]));
        #pragma unroll
        for (int e = 0; e < 4; ++e)
            vtg[(bh * 4 + e) * SS + s] = (_Float16)v[e];
    }
}

// ---------------------------------------------------------------------------
// Kernel 2: MFMA flash attention, DEPTH-3 QK pipeline (stages A/B/C,
// statically named, no runtime indexing). Depth-2 (R16) gave +7% — latency
// cover is the active lever; depth-3 keeps VGPR <=128 so 4 blocks/CU holds
// (depth-4 would cross 128 and halve occupancy). 64 tiles = 21 rounds x 3
// + 1 tail tile (no reissue). s_setprio(1) wraps PV mfma pairs (T5).
//   S^T = mfma(A=K-tile, B=Q); P~ = exp2(S^T)  (no shift — cancels);
//   O^T += mfma(A=V^T(+ones row -> l), B=P~ via cvt_pkrtz+permlane32_swap)
// Grid = B*H * 16 blocks, 4 waves/block.
// ---------------------------------------------------------------------------
#define LDS_K    0
#define LDS_VT   16384
#define VT_STRIDE 4112          // (2048+8) f16 -> breaks bank alignment
#define LDS_Z    36944          // 128 B zero slot (padded-lane reads)
#define LDS_SIZE 37376
#define NT       (SS / 32)      // 64 j-tiles

__global__ __launch_bounds__(256, 4) void k_attn(
    const uint2* __restrict__ qws16,
    const uint2* __restrict__ kws16,
    const unsigned* __restrict__ vtg,   // u32 view of VT f16 [bh][4][SS]
    float4* __restrict__ ows)           // [B*H*S] normalized attention out
{
    __shared__ __align__(16) char lds[LDS_SIZE];

    const int t      = threadIdx.x;
    const int bh     = blockIdx.x >> 4;
    const int w      = t >> 6;
    const int iblock = (blockIdx.x & 15) * 4 + w;
    const int lane   = t & 63;
    const int c31    = lane & 31;

    // ---- stage K (16 KB: uint2 per key) ----
    const uint2* kg = kws16 + bh * SS;
    for (int i = t; i < SS; i += 256)
        *(uint2*)(lds + LDS_K + i * 8) = kg[i];
    // ---- stage V^T rows 0..3 (f16, padded row stride) ----
    const unsigned* vg = vtg + bh * 4 * (SS / 2);
    for (int i = t; i < 4 * (SS / 2); i += 256) {
        const int cc = i >> 10, col = i & 1023;
        *(unsigned*)(lds + LDS_VT + cc * VT_STRIDE + col * 4) = vg[i];
    }
    // ---- ones row (c = 4) for the l-accumulator ----
    for (int i = t; i < SS / 2; i += 256)
        *(unsigned*)(lds + LDS_VT + 4 * VT_STRIDE + i * 4) = 0x3C003C00u;
    // ---- zero slot ----
    if (t < 32) *(unsigned*)(lds + LDS_Z + t * 4) = 0u;
    __syncthreads();

    // Q B-frag (fixed per wave): lane holds col i=lane&31, k=d (lanes>=32 pad 0)
    uint2 qq = qws16[bh * SS + iblock * 32 + c31];
    if (lane >= 32) { qq.x = 0u; qq.y = 0u; }
    const f16x8 bq = frag2(qq.x, qq.y);

    // per-lane LDS addresses (padded lanes read the zero slot, never step)
    int kaddr = (lane < 32) ? (LDS_K + lane * 8) : LDS_Z;
    const int kstep = (lane < 32) ? 256 : 0;            // 32 keys * 8 B
    int vaddr = (c31 < 5) ? (LDS_VT + c31 * VT_STRIDE + (lane >> 5) * 16) : LDS_Z;
    const int vstep = (c31 < 5) ? 64 : 0;               // 32 j * 2 B

    f32x16 oacc = {0,0,0,0,0,0,0,0,0,0,0,0,0,0,0,0};
    const f32x16 zc = {0,0,0,0,0,0,0,0,0,0,0,0,0,0,0,0};

    // full tile body: exps(dX) -> reissue dX (tile +3) -> PV with vvX
    auto tile_body = [&](f32x16& dX, uint2& kkX, uint4& vvX0, uint4& vvX1) {
        float p[16];
        #pragma unroll
        for (int r = 0; r < 16; ++r) p[r] = fast_exp2(dX[r]);

        // reissue this stage: scores for tile jt+3 (WAR after exps read dX)
        dX = __builtin_amdgcn_mfma_f32_32x32x16_f16(frag2(kkX.x, kkX.y), bq, zc, 0, 0, 0);
        kkX = *(const uint2*)(lds + kaddr); kaddr += kstep;

        const f16x8 av0 = frag4(vvX0);
        const f16x8 av1 = frag4(vvX1);
        vvX0 = *(const uint4*)(lds + vaddr);
        vvX1 = *(const uint4*)(lds + vaddr + 32); vaddr += vstep;

        const int pk01 = cvtpk(p[0],  p[1]),  pk23 = cvtpk(p[2],  p[3]);
        const int pk45 = cvtpk(p[4],  p[5]),  pk67 = cvtpk(p[6],  p[7]);
        const int pk89 = cvtpk(p[8],  p[9]),  pkAB = cvtpk(p[10], p[11]);
        const int pkCD = cvtpk(p[12], p[13]), pkEF = cvtpk(p[14], p[15]);

        int B0, B1, B2, B3, C0, C1, C2, C3;
        swap32(pk01, pk45, lane, B0, B2);
        swap32(pk23, pk67, lane, B1, B3);
        swap32(pk89, pkCD, lane, C0, C2);
        swap32(pkAB, pkEF, lane, C1, C3);

        __builtin_amdgcn_s_setprio(1);
        oacc = __builtin_amdgcn_mfma_f32_32x32x16_f16(av0, fragi(B0, B1, B2, B3), oacc, 0, 0, 0);
        oacc = __builtin_amdgcn_mfma_f32_32x32x16_f16(av1, fragi(C0, C1, C2, C3), oacc, 0, 0, 0);
        __builtin_amdgcn_s_setprio(0);
    };

    // tail body: no reissue, consume dX and vvX only
    auto tile_tail = [&](f32x16& dX, uint4 vvX0, uint4 vvX1) {
        float p[16];
        #pragma unroll
        for (int r = 0; r < 16; ++r) p[r] = fast_exp2(dX[r]);

        const f16x8 av0 = frag4(vvX0);
        const f16x8 av1 = frag4(vvX1);

        const int pk01 = cvtpk(p[0],  p[1]),  pk23 = cvtpk(p[2],  p[3]);
        const int pk45 = cvtpk(p[4],  p[5]),  pk67 = cvtpk(p[6],  p[7]);
        const int pk89 = cvtpk(p[8],  p[9]),  pkAB = cvtpk(p[10], p[11]);
        const int pkCD = cvtpk(p[12], p[13]), pkEF = cvtpk(p[14], p[15]);

        int B0, B1, B2, B3, C0, C1, C2, C3;
        swap32(pk01, pk45, lane, B0, B2);
        swap32(pk23, pk67, lane, B1, B3);
        swap32(pk89, pkCD, lane, C0, C2);
        swap32(pkAB, pkEF, lane, C1, C3);

        oacc = __builtin_amdgcn_mfma_f32_32x32x16_f16(av0, fragi(B0, B1, B2, B3), oacc, 0, 0, 0);
        oacc = __builtin_amdgcn_mfma_f32_32x32x16_f16(av1, fragi(C0, C1, C2, C3), oacc, 0, 0, 0);
    };

    // ---- prologue: tiles 0..2 in flight ----
    uint2 kkA = *(const uint2*)(lds + kaddr); kaddr += kstep;   // K[0]
    uint2 kkB = *(const uint2*)(lds + kaddr); kaddr += kstep;   // K[1]
    uint2 kkC = *(const uint2*)(lds + kaddr); kaddr += kstep;   // K[2]
    uint4 vvA0 = *(const uint4*)(lds + vaddr);                  // V[0]
    uint4 vvA1 = *(const uint4*)(lds + vaddr + 32); vaddr += vstep;
    uint4 vvB0 = *(const uint4*)(lds + vaddr);                  // V[1]
    uint4 vvB1 = *(const uint4*)(lds + vaddr + 32); vaddr += vstep;
    uint4 vvC0 = *(const uint4*)(lds + vaddr);                  // V[2]
    uint4 vvC1 = *(const uint4*)(lds + vaddr + 32); vaddr += vstep;

    f32x16 dA = __builtin_amdgcn_mfma_f32_32x32x16_f16(frag2(kkA.x, kkA.y), bq, zc, 0, 0, 0);
    kkA = *(const uint2*)(lds + kaddr); kaddr += kstep;         // K[3]
    f32x16 dB = __builtin_amdgcn_mfma_f32_32x32x16_f16(frag2(kkB.x, kkB.y), bq, zc, 0, 0, 0);
    kkB = *(const uint2*)(lds + kaddr); kaddr += kstep;         // K[4]
    f32x16 dC = __builtin_amdgcn_mfma_f32_32x32x16_f16(frag2(kkC.x, kkC.y), bq, zc, 0, 0, 0);
    kkC = *(const uint2*)(lds + kaddr); kaddr += kstep;         // K[5]

    // 21 rounds x 3 tiles = tiles 0..62
    for (int jt = 0; jt < NT - 1; jt += 3) {
        tile_body(dA, kkA, vvA0, vvA1);
        tile_body(dB, kkB, vvB0, vvB1);
        tile_body(dC, kkC, vvC0, vvC1);
    }
    // tail: tile 63 (dA was reissued for tile 63 in the last round; vvA holds V[63])
    tile_tail(dA, vvA0, vvA1);

    // l sits in reg0 of lanes>=32 (row c=4); bring to lanes<32 and normalize.
    union { float f; int i; } u0; u0.f = oacc[0];
    int s0i, s1i;
    swap32(u0.i, u0.i, lane, s0i, s1i);
    union { int i; float f; } ul; ul.i = s1i;      // lanes<32: l from lane+32
    if (lane < 32) {
        const float inv = 1.0f / ul.f;
        ows[bh * SS + iblock * 32 + lane] =
            make_float4(oacc[0] * inv, oacc[1] * inv, oacc[2] * inv, oacc[3] * inv);
    }
}

// ---------------------------------------------------------------------------
// Kernel 3: epilogue (unchanged). O already normalized.
// ---------------------------------------------------------------------------
__global__ __launch_bounds__(256) void k_epilogue(
    const float* __restrict__ x,      // [B,S]
    const float* __restrict__ Wo,     // [8,8]
    const float* __restrict__ bo,     // [8]
    const float4* __restrict__ ows,
    const float4* __restrict__ mmws,
    float* __restrict__ out)          // seasonal [B*S] then trend [B*S]
{
    const int pos = blockIdx.x * 256 + threadIdx.x;  // = b*S + s
    const int b = pos / SS;
    const int s = pos % SS;

    const float4 o0 = ows[(b * SH + 0) * SS + s];
    const float4 o1 = ows[(b * SH + 1) * SS + s];
    const float ov[8] = {o0.x, o0.y, o0.z, o0.w, o1.x, o1.y, o1.z, o1.w};

    float g[8];
    float m = -1e30f;
    #pragma unroll
    for (int e = 0; e < 8; ++e) {
        float acc = bo[e];
        #pragma unroll
        for (int f = 0; f < 8; ++f) acc += ov[f] * Wo[e * 8 + f];
        g[e] = acc;
        m = fmaxf(m, acc);
    }
    float l = 0.0f;
    #pragma unroll
    for (int e = 0; e < 8; ++e) { g[e] = __expf(g[e] - m); l += g[e]; }
    const float inv = 1.0f / l;

    const float4 mm0 = mmws[pos * 2 + 0];
    const float4 mm1 = mmws[pos * 2 + 1];
    const float mv[8] = {mm0.x, mm0.y, mm0.z, mm0.w, mm1.x, mm1.y, mm1.z, mm1.w};

    float trend = 0.0f;
    #pragma unroll
    for (int e = 0; e < 8; ++e) trend += g[e] * inv * mv[e];

    out[pos]           = x[pos] - trend;   // seasonal
    out[SB * SS + pos] = trend;            // trend
}

extern "C" void kernel_launch(void* const* d_in, const int* in_sizes, int n_in,
                              void* d_out, int out_size, void* d_ws, size_t ws_size,
                              hipStream_t stream) {
    const float* x  = (const float*)d_in[0];
    const float* Wq = (const float*)d_in[1];
    const float* Wk = (const float*)d_in[2];
    const float* Wv = (const float*)d_in[3];
    const float* Wo = (const float*)d_in[4];
    const float* bo = (const float*)d_in[5];

    uint2*     qws16 = (uint2*)d_ws;                        // 1 MB
    uint2*     kws16 = qws16 + SB * SH * SS;                // 1 MB
    _Float16*  vtg   = (_Float16*)(kws16 + SB * SH * SS);   // 1 MB  [bh][4][S]
    float4*    mmws  = (float4*)(vtg + SB * SH * 4 * SS);   // 2 MB
    float4*    ows   = mmws + SB * SS * 2;                  // 2 MB

    k_ma_qkv<<<SB * (SS / 256), 256, 0, stream>>>(x, Wq, Wk, Wv, qws16, kws16, vtg, mmws);
    k_attn<<<SB * SH * 16, 256, 0, stream>>>(qws16, kws16, (const unsigned*)vtg, ows);
    k_epilogue<<<(SB * SS) / 256, 256, 0, stream>>>(x, Wo, bo, ows, mmws, (float*)d_out);
}

// Round 18
// 44.974 us; speedup vs baseline: 1.0807x; 1.0807x over previous
//
#include <hip/hip_runtime.h>

#define SB 32      // batch
#define SS 2048    // sequence
#define SH 2       // heads
#define SD 4       // head dim
#define SE 8       // embed

#define LOG2E 1.44269504f

typedef float    f32x16 __attribute__((ext_vector_type(16)));
typedef _Float16 f16x8  __attribute__((ext_vector_type(8)));
typedef _Float16 f16x4  __attribute__((ext_vector_type(4)));

static __device__ __forceinline__ float fast_exp2(float x) {
#if __has_builtin(__builtin_amdgcn_exp2f)
    return __builtin_amdgcn_exp2f(x);
#else
    return exp2f(x);
#endif
}

static __device__ __forceinline__ int cvtpk(float a, float b) {
    auto h = __builtin_amdgcn_cvt_pkrtz(a, b);
    union { decltype(h) hh; int i; } u; u.hh = h; return u.i;
}

// exchange register halves across the lane<32 / lane>=32 boundary
static __device__ __forceinline__ void swap32(int a, int b, int lane, int& r0, int& r1) {
#if __has_builtin(__builtin_amdgcn_permlane32_swap)
    auto r = __builtin_amdgcn_permlane32_swap(a, b, false, false);
    r0 = r[0]; r1 = r[1];
#else
    const int blo = __builtin_amdgcn_ds_bpermute((lane & 31) << 2, b);
    const int ahi = __builtin_amdgcn_ds_bpermute(((lane ^ 32) & 63) << 2, a);
    r0 = (lane < 32) ? a : blo;
    r1 = (lane < 32) ? ahi : b;
#endif
}

static __device__ __forceinline__ f16x8 frag2(unsigned x, unsigned y) {
    union { unsigned u[4]; f16x8 h; } c;
    c.u[0] = x; c.u[1] = y; c.u[2] = 0; c.u[3] = 0; return c.h;
}
static __device__ __forceinline__ f16x8 frag4(uint4 v) {
    union { uint4 u; f16x8 h; } c; c.u = v; return c.h;
}
static __device__ __forceinline__ f16x8 fragi(int a, int b, int c_, int d) {
    union { int u[4]; f16x8 h; } c;
    c.u[0] = a; c.u[1] = b; c.u[2] = c_; c.u[3] = d; return c.h;
}

// ---- QK mfma: prefer 32x32x8 (K=8 >= D=4; 2-reg operands) ----
#if __has_builtin(__builtin_amdgcn_mfma_f32_32x32x8f16)
typedef f16x4 qkfrag;
static __device__ __forceinline__ qkfrag make_qk(unsigned x, unsigned y) {
    union { unsigned u[2]; f16x4 h; } c; c.u[0] = x; c.u[1] = y; return c.h;
}
static __device__ __forceinline__ f32x16 qk_mfma(qkfrag a, qkfrag b, f32x16 c) {
    return __builtin_amdgcn_mfma_f32_32x32x8f16(a, b, c, 0, 0, 0);
}
#else
typedef f16x8 qkfrag;
static __device__ __forceinline__ qkfrag make_qk(unsigned x, unsigned y) {
    return frag2(x, y);
}
static __device__ __forceinline__ f32x16 qk_mfma(qkfrag a, qkfrag b, f32x16 c) {
    return __builtin_amdgcn_mfma_f32_32x32x16_f16(a, b, c, 0, 0, 0);
}
#endif

union u32h2 { unsigned u; _Float16 h[2]; };
static __device__ __forceinline__ unsigned packh2(float a, float b) {
    u32h2 c; c.h[0] = (_Float16)a; c.h[1] = (_Float16)b; return c.u;
}

// ---------------------------------------------------------------------------
// Kernel 1: moving averages + QKV projection (unchanged).
// ---------------------------------------------------------------------------
__global__ __launch_bounds__(256) void k_ma_qkv(
    const float* __restrict__ x,      // [B,S]
    const float* __restrict__ Wq,     // [4,4] row-major W[e*4+d]
    const float* __restrict__ Wk,
    const float* __restrict__ Wv,
    uint2* __restrict__ qws16,        // [B*H*S] packed f16 {q01,q23}
    uint2* __restrict__ kws16,        // [B*H*S]
    _Float16* __restrict__ vtg,       // [B*H][4][S] V transposed, f16
    float4* __restrict__ mmws)        // [B*S*2]
{
    __shared__ float xs[272];

    const int tile = blockIdx.x % (SS / 256);
    const int b    = blockIdx.x / (SS / 256);
    const int s0   = tile * 256;
    const float* xrow = x + b * SS;

    for (int i = threadIdx.x; i < 272; i += 256) {
        int idx = s0 - 8 + i;
        idx = min(max(idx, 0), SS - 1);
        xs[i] = xrow[idx];
    }
    __syncthreads();

    const int t = threadIdx.x;
    const int s = s0 + t;

    float mmv[8];
    float c = xs[8 + t];
    #pragma unroll
    for (int h = 1; h <= 8; ++h) {
        c += xs[8 + t - h] + xs[8 + t + h];
        mmv[h - 1] = c * (1.0f / (float)(2 * h + 1));
    }

    mmws[(b * SS + s) * 2 + 0] = make_float4(mmv[0], mmv[1], mmv[2], mmv[3]);
    mmws[(b * SS + s) * 2 + 1] = make_float4(mmv[4], mmv[5], mmv[6], mmv[7]);

    const float qscale = 0.5f * LOG2E;  // 1/sqrt(D) * log2(e)
    #pragma unroll
    for (int h = 0; h < SH; ++h) {
        const float t0 = mmv[h * 4 + 0];
        const float t1 = mmv[h * 4 + 1];
        const float t2 = mmv[h * 4 + 2];
        const float t3 = mmv[h * 4 + 3];
        float q[4], k[4], v[4];
        #pragma unroll
        for (int e = 0; e < 4; ++e) {
            q[e] = (t0 * Wq[e * 4 + 0] + t1 * Wq[e * 4 + 1] +
                    t2 * Wq[e * 4 + 2] + t3 * Wq[e * 4 + 3]) * qscale;
            k[e] =  t0 * Wk[e * 4 + 0] + t1 * Wk[e * 4 + 1] +
                    t2 * Wk[e * 4 + 2] + t3 * Wk[e * 4 + 3];
            v[e] =  t0 * Wv[e * 4 + 0] + t1 * Wv[e * 4 + 1] +
                    t2 * Wv[e * 4 + 2] + t3 * Wv[e * 4 + 3];
        }
        const int bh  = b * SH + h;
        const int idx = bh * SS + s;
        qws16[idx] = make_uint2(packh2(q[0], q[1]), packh2(q[2], q[3]));
        kws16[idx] = make_uint2(packh2(k[0], k[1]), packh2(k[2], k[3]));
        #pragma unroll
        for (int e = 0; e < 4; ++e)
            vtg[(bh * 4 + e) * SS + s] = (_Float16)v[e];
    }
}

// ---------------------------------------------------------------------------
// Kernel 2: MFMA flash attention, TWO i-blocks per wave. The K-frag, V-frag,
// LDS reads, and loop overhead are shared between the two 32-row q-blocks
// (per-score overhead /2), and the two independent QK->exp->PV chains give
// depth-2-equivalent latency cover natively (R16 evidence). QK uses
// mfma_32x32x8_f16 (K=8 >= D=4, 2-reg operands, half the QK pipe cost; hi
// lanes hold k=4..7 zeros in BOTH operands -> contribution exactly 0).
//   S^T = qk_mfma(K-tile, Q_i); P~ = exp2(S^T)  (no shift — cancels);
//   O^T_i += mfma16(V^T(+ones row -> l), P~ via cvt_pkrtz+permlane32_swap)
// Grid = B*H * 8 blocks, 4 waves/block, 2 i-blocks/wave = 64 i-blocks/(b,h).
// ---------------------------------------------------------------------------
#define LDS_K    0
#define LDS_VT   16384
#define VT_STRIDE 4112          // (2048+8) f16 -> breaks bank alignment
#define LDS_Z    36944          // 128 B zero slot (padded-lane reads)
#define LDS_SIZE 37376
#define NT       (SS / 32)      // 64 j-tiles

__global__ __launch_bounds__(256, 2) void k_attn(
    const uint2* __restrict__ qws16,
    const uint2* __restrict__ kws16,
    const unsigned* __restrict__ vtg,   // u32 view of VT f16 [bh][4][SS]
    float4* __restrict__ ows)           // [B*H*S] normalized attention out
{
    __shared__ __align__(16) char lds[LDS_SIZE];

    const int t    = threadIdx.x;
    const int bh   = blockIdx.x >> 3;
    const int part = blockIdx.x & 7;
    const int w    = t >> 6;
    const int ib0  = part * 8 + w;        // first i-block
    const int ib1  = ib0 + 4;             // second i-block
    const int lane = t & 63;
    const int c31  = lane & 31;

    // ---- stage K (16 KB: uint2 per key) ----
    const uint2* kg = kws16 + bh * SS;
    for (int i = t; i < SS; i += 256)
        *(uint2*)(lds + LDS_K + i * 8) = kg[i];
    // ---- stage V^T rows 0..3 (f16, padded row stride) ----
    const unsigned* vg = vtg + bh * 4 * (SS / 2);
    for (int i = t; i < 4 * (SS / 2); i += 256) {
        const int cc = i >> 10, col = i & 1023;
        *(unsigned*)(lds + LDS_VT + cc * VT_STRIDE + col * 4) = vg[i];
    }
    // ---- ones row (c = 4) for the l-accumulator ----
    for (int i = t; i < SS / 2; i += 256)
        *(unsigned*)(lds + LDS_VT + 4 * VT_STRIDE + i * 4) = 0x3C003C00u;
    // ---- zero slot ----
    if (t < 32) *(unsigned*)(lds + LDS_Z + t * 4) = 0u;
    __syncthreads();

    // Q B-frags (fixed per wave): lane holds col i=lane&31, k=d (hi lanes 0)
    uint2 qq0 = qws16[bh * SS + ib0 * 32 + c31];
    uint2 qq1 = qws16[bh * SS + ib1 * 32 + c31];
    if (lane >= 32) { qq0.x = 0u; qq0.y = 0u; qq1.x = 0u; qq1.y = 0u; }
    const qkfrag bq0 = make_qk(qq0.x, qq0.y);
    const qkfrag bq1 = make_qk(qq1.x, qq1.y);

    // per-lane LDS addresses (padded lanes read the zero slot, never step)
    int kaddr = (lane < 32) ? (LDS_K + lane * 8) : LDS_Z;
    const int kstep = (lane < 32) ? 256 : 0;            // 32 keys * 8 B
    int vaddr = (c31 < 5) ? (LDS_VT + c31 * VT_STRIDE + (lane >> 5) * 16) : LDS_Z;
    const int vstep = (c31 < 5) ? 64 : 0;               // 32 j * 2 B

    f32x16 oacc0 = {0,0,0,0,0,0,0,0,0,0,0,0,0,0,0,0};
    f32x16 oacc1 = {0,0,0,0,0,0,0,0,0,0,0,0,0,0,0,0};
    const f32x16 zc = {0,0,0,0,0,0,0,0,0,0,0,0,0,0,0,0};

    // ---- prologue: tile 0 scores for both i-blocks in flight ----
    uint2 kk = *(const uint2*)(lds + kaddr); kaddr += kstep;      // K[0]
    f32x16 d0 = qk_mfma(make_qk(kk.x, kk.y), bq0, zc);
    f32x16 d1 = qk_mfma(make_qk(kk.x, kk.y), bq1, zc);
    kk = *(const uint2*)(lds + kaddr); kaddr += kstep;            // K[1]
    uint4 vv0 = *(const uint4*)(lds + vaddr);                     // V[0]
    uint4 vv1 = *(const uint4*)(lds + vaddr + 32); vaddr += vstep;

    for (int jt = 0; jt < NT; ++jt) {
        const qkfrag ak = make_qk(kk.x, kk.y);    // K[jt+1]

        // ---- i-block 0: exp + frag build, then reissue its QK (tile jt+1)
        float p[16];
        #pragma unroll
        for (int r = 0; r < 16; ++r) p[r] = fast_exp2(d0[r]);
        int F00, F01, F02, F03;
        {
            const int pk01 = cvtpk(p[0],  p[1]),  pk23 = cvtpk(p[2],  p[3]);
            const int pk45 = cvtpk(p[4],  p[5]),  pk67 = cvtpk(p[6],  p[7]);
            const int pk89 = cvtpk(p[8],  p[9]),  pkAB = cvtpk(p[10], p[11]);
            const int pkCD = cvtpk(p[12], p[13]), pkEF = cvtpk(p[14], p[15]);
            int B0, B1, B2, B3, C0, C1, C2, C3;
            swap32(pk01, pk45, lane, B0, B2);
            swap32(pk23, pk67, lane, B1, B3);
            swap32(pk89, pkCD, lane, C0, C2);
            swap32(pkAB, pkEF, lane, C1, C3);
            F00 = B0; F01 = B1; F02 = B2; F03 = B3;
            // stash second half via regs below
            d0 = qk_mfma(ak, bq0, zc);            // reissue i0 (tile jt+1)
            // PV for i0, j 16..31 frag:
            const f16x8 bpC = fragi(C0, C1, C2, C3);
            const f16x8 av0 = frag4(vv0);
            const f16x8 av1 = frag4(vv1);
            __builtin_amdgcn_s_setprio(1);
            oacc0 = __builtin_amdgcn_mfma_f32_32x32x16_f16(av0, fragi(F00, F01, F02, F03), oacc0, 0, 0, 0);
            oacc0 = __builtin_amdgcn_mfma_f32_32x32x16_f16(av1, bpC, oacc0, 0, 0, 0);
            __builtin_amdgcn_s_setprio(0);
        }

        // ---- i-block 1: exp + frag build, reissue, PV
        #pragma unroll
        for (int r = 0; r < 16; ++r) p[r] = fast_exp2(d1[r]);
        {
            const int pk01 = cvtpk(p[0],  p[1]),  pk23 = cvtpk(p[2],  p[3]);
            const int pk45 = cvtpk(p[4],  p[5]),  pk67 = cvtpk(p[6],  p[7]);
            const int pk89 = cvtpk(p[8],  p[9]),  pkAB = cvtpk(p[10], p[11]);
            const int pkCD = cvtpk(p[12], p[13]), pkEF = cvtpk(p[14], p[15]);
            int B0, B1, B2, B3, C0, C1, C2, C3;
            swap32(pk01, pk45, lane, B0, B2);
            swap32(pk23, pk67, lane, B1, B3);
            swap32(pk89, pkCD, lane, C0, C2);
            swap32(pkAB, pkEF, lane, C1, C3);
            d1 = qk_mfma(ak, bq1, zc);            // reissue i1 (tile jt+1)
            const f16x8 av0 = frag4(vv0);
            const f16x8 av1 = frag4(vv1);
            // advance K/V streams for the next tile
            kk  = *(const uint2*)(lds + kaddr); kaddr += kstep;   // K[jt+2]
            vv0 = *(const uint4*)(lds + vaddr);                   // V[jt+1]
            vv1 = *(const uint4*)(lds + vaddr + 32); vaddr += vstep;
            __builtin_amdgcn_s_setprio(1);
            oacc1 = __builtin_amdgcn_mfma_f32_32x32x16_f16(av0, fragi(B0, B1, B2, B3), oacc1, 0, 0, 0);
            oacc1 = __builtin_amdgcn_mfma_f32_32x32x16_f16(av1, fragi(C0, C1, C2, C3), oacc1, 0, 0, 0);
            __builtin_amdgcn_s_setprio(0);
        }
    }

    // l sits in reg0 of lanes>=32 (row c=4); bring to lanes<32 and normalize.
    {
        union { float f; int i; } u0; u0.f = oacc0[0];
        int s0i, s1i;
        swap32(u0.i, u0.i, lane, s0i, s1i);
        union { int i; float f; } ul; ul.i = s1i;
        if (lane < 32) {
            const float inv = 1.0f / ul.f;
            ows[bh * SS + ib0 * 32 + lane] =
                make_float4(oacc0[0] * inv, oacc0[1] * inv, oacc0[2] * inv, oacc0[3] * inv);
        }
    }
    {
        union { float f; int i; } u0; u0.f = oacc1[0];
        int s0i, s1i;
        swap32(u0.i, u0.i, lane, s0i, s1i);
        union { int i; float f; } ul; ul.i = s1i;
        if (lane < 32) {
            const float inv = 1.0f / ul.f;
            ows[bh * SS + ib1 * 32 + lane] =
                make_float4(oacc1[0] * inv, oacc1[1] * inv, oacc1[2] * inv, oacc1[3] * inv);
        }
    }
}

// ---------------------------------------------------------------------------
// Kernel 3: epilogue (unchanged). O already normalized.
// ---------------------------------------------------------------------------
__global__ __launch_bounds__(256) void k_epilogue(
    const float* __restrict__ x,      // [B,S]
    const float* __restrict__ Wo,     // [8,8]
    const float* __restrict__ bo,     // [8]
    const float4* __restrict__ ows,
    const float4* __restrict__ mmws,
    float* __restrict__ out)          // seasonal [B*S] then trend [B*S]
{
    const int pos = blockIdx.x * 256 + threadIdx.x;  // = b*S + s
    const int b = pos / SS;
    const int s = pos % SS;

    const float4 o0 = ows[(b * SH + 0) * SS + s];
    const float4 o1 = ows[(b * SH + 1) * SS + s];
    const float ov[8] = {o0.x, o0.y, o0.z, o0.w, o1.x, o1.y, o1.z, o1.w};

    float g[8];
    float m = -1e30f;
    #pragma unroll
    for (int e = 0; e < 8; ++e) {
        float acc = bo[e];
        #pragma unroll
        for (int f = 0; f < 8; ++f) acc += ov[f] * Wo[e * 8 + f];
        g[e] = acc;
        m = fmaxf(m, acc);
    }
    float l = 0.0f;
    #pragma unroll
    for (int e = 0; e < 8; ++e) { g[e] = __expf(g[e] - m); l += g[e]; }
    const float inv = 1.0f / l;

    const float4 mm0 = mmws[pos * 2 + 0];
    const float4 mm1 = mmws[pos * 2 + 1];
    const float mv[8] = {mm0.x, mm0.y, mm0.z, mm0.w, mm1.x, mm1.y, mm1.z, mm1.w};

    float trend = 0.0f;
    #pragma unroll
    for (int e = 0; e < 8; ++e) trend += g[e] * inv * mv[e];

    out[pos]           = x[pos] - trend;   // seasonal
    out[SB * SS + pos] = trend;            // trend
}

extern "C" void kernel_launch(void* const* d_in, const int* in_sizes, int n_in,
                              void* d_out, int out_size, void* d_ws, size_t ws_size,
                              hipStream_t stream) {
    const float* x  = (const float*)d_in[0];
    const float* Wq = (const float*)d_in[1];
    const float* Wk = (const float*)d_in[2];
    const float* Wv = (const float*)d_in[3];
    const float* Wo = (const float*)d_in[4];
    const float* bo = (const float*)d_in[5];

    uint2*     qws16 = (uint2*)d_ws;                        // 1 MB
    uint2*     kws16 = qws16 + SB * SH * SS;                // 1 MB
    _Float16*  vtg   = (_Float16*)(kws16 + SB * SH * SS);   // 1 MB  [bh][4][S]
    float4*    mmws  = (float4*)(vtg + SB * SH * 4 * SS);   // 2 MB
    float4*    ows   = mmws + SB * SS * 2;                  // 2 MB

    k_ma_qkv<<<SB * (SS / 256), 256, 0, stream>>>(x, Wq, Wk, Wv, qws16, kws16, vtg, mmws);
    k_attn<<<SB * SH * 8, 256, 0, stream>>>(qws16, kws16, (const unsigned*)vtg, ows);
    k_epilogue<<<(SB * SS) / 256, 256, 0, stream>>>(x, Wo, bo, ows, mmws, (float*)d_out);
}

// Round 19
// 41.658 us; speedup vs baseline: 1.1667x; 1.0796x over previous
//
#include <hip/hip_runtime.h>

#define SB 32      // batch
#define SS 2048    // sequence
#define SH 2       // heads
#define SD 4       // head dim
#define SE 8       // embed

#define LOG2E 1.44269504f

typedef float    f32x16 __attribute__((ext_vector_type(16)));
typedef _Float16 f16x8  __attribute__((ext_vector_type(8)));
typedef _Float16 f16x4  __attribute__((ext_vector_type(4)));

static __device__ __forceinline__ float fast_exp2(float x) {
#if __has_builtin(__builtin_amdgcn_exp2f)
    return __builtin_amdgcn_exp2f(x);
#else
    return exp2f(x);
#endif
}

static __device__ __forceinline__ int cvtpk(float a, float b) {
    auto h = __builtin_amdgcn_cvt_pkrtz(a, b);
    union { decltype(h) hh; int i; } u; u.hh = h; return u.i;
}

// exchange register halves across the lane<32 / lane>=32 boundary
// (only used once, for the final l-extraction)
static __device__ __forceinline__ void swap32(int a, int b, int lane, int& r0, int& r1) {
#if __has_builtin(__builtin_amdgcn_permlane32_swap)
    auto r = __builtin_amdgcn_permlane32_swap(a, b, false, false);
    r0 = r[0]; r1 = r[1];
#else
    const int blo = __builtin_amdgcn_ds_bpermute((lane & 31) << 2, b);
    const int ahi = __builtin_amdgcn_ds_bpermute(((lane ^ 32) & 63) << 2, a);
    r0 = (lane < 32) ? a : blo;
    r1 = (lane < 32) ? ahi : b;
#endif
}

static __device__ __forceinline__ f16x8 frag2(unsigned x, unsigned y) {
    union { unsigned u[4]; f16x8 h; } c;
    c.u[0] = x; c.u[1] = y; c.u[2] = 0; c.u[3] = 0; return c.h;
}
static __device__ __forceinline__ f16x8 frag4(uint4 v) {
    union { uint4 u; f16x8 h; } c; c.u = v; return c.h;
}
static __device__ __forceinline__ f16x8 fragi(int a, int b, int c_, int d) {
    union { int u[4]; f16x8 h; } c;
    c.u[0] = a; c.u[1] = b; c.u[2] = c_; c.u[3] = d; return c.h;
}

// ---- QK mfma: prefer 32x32x8 (K=8 >= D=4; 2-reg operands) ----
#if __has_builtin(__builtin_amdgcn_mfma_f32_32x32x8f16)
typedef f16x4 qkfrag;
static __device__ __forceinline__ qkfrag make_qk(unsigned x, unsigned y) {
    union { unsigned u[2]; f16x4 h; } c; c.u[0] = x; c.u[1] = y; return c.h;
}
static __device__ __forceinline__ f32x16 qk_mfma(qkfrag a, qkfrag b, f32x16 c) {
    return __builtin_amdgcn_mfma_f32_32x32x8f16(a, b, c, 0, 0, 0);
}
#else
typedef f16x8 qkfrag;
static __device__ __forceinline__ qkfrag make_qk(unsigned x, unsigned y) {
    return frag2(x, y);
}
static __device__ __forceinline__ f32x16 qk_mfma(qkfrag a, qkfrag b, f32x16 c) {
    return __builtin_amdgcn_mfma_f32_32x32x16_f16(a, b, c, 0, 0, 0);
}
#endif

union u32h2 { unsigned u; _Float16 h[2]; };
static __device__ __forceinline__ unsigned packh2(float a, float b) {
    u32h2 c; c.h[0] = (_Float16)a; c.h[1] = (_Float16)b; return c.u;
}

// ---------------------------------------------------------------------------
// Kernel 1: moving averages + QKV projection. V is written at the
// kappa-permuted position (swap bits 2<->3 of the sequence index,
// involution, period 16): this pre-aligns V^T columns with the PV B-frag
// built DIRECTLY from the QK C-layout registers, eliminating all
// permlane32_swap ops in the attention hot loop. PV's key-sum is over the
// same set, so the result is exact.
// ---------------------------------------------------------------------------
__global__ __launch_bounds__(256) void k_ma_qkv(
    const float* __restrict__ x,      // [B,S]
    const float* __restrict__ Wq,     // [4,4] row-major W[e*4+d]
    const float* __restrict__ Wk,
    const float* __restrict__ Wv,
    uint2* __restrict__ qws16,        // [B*H*S] packed f16 {q01,q23}
    uint2* __restrict__ kws16,        // [B*H*S]
    _Float16* __restrict__ vtg,       // [B*H][4][S] V transposed, f16, kappa-permuted
    float4* __restrict__ mmws)        // [B*S*2]
{
    __shared__ float xs[272];

    const int tile = blockIdx.x % (SS / 256);
    const int b    = blockIdx.x / (SS / 256);
    const int s0   = tile * 256;
    const float* xrow = x + b * SS;

    for (int i = threadIdx.x; i < 272; i += 256) {
        int idx = s0 - 8 + i;
        idx = min(max(idx, 0), SS - 1);
        xs[i] = xrow[idx];
    }
    __syncthreads();

    const int t = threadIdx.x;
    const int s = s0 + t;
    // kappa: swap bits 2 and 3 of s (within each 16-key group)
    const int sp = (s & ~12) | (((s >> 2) & 1) << 3) | (((s >> 3) & 1) << 2);

    float mmv[8];
    float c = xs[8 + t];
    #pragma unroll
    for (int h = 1; h <= 8; ++h) {
        c += xs[8 + t - h] + xs[8 + t + h];
        mmv[h - 1] = c * (1.0f / (float)(2 * h + 1));
    }

    mmws[(b * SS + s) * 2 + 0] = make_float4(mmv[0], mmv[1], mmv[2], mmv[3]);
    mmws[(b * SS + s) * 2 + 1] = make_float4(mmv[4], mmv[5], mmv[6], mmv[7]);

    const float qscale = 0.5f * LOG2E;  // 1/sqrt(D) * log2(e)
    #pragma unroll
    for (int h = 0; h < SH; ++h) {
        const float t0 = mmv[h * 4 + 0];
        const float t1 = mmv[h * 4 + 1];
        const float t2 = mmv[h * 4 + 2];
        const float t3 = mmv[h * 4 + 3];
        float q[4], k[4], v[4];
        #pragma unroll
        for (int e = 0; e < 4; ++e) {
            q[e] = (t0 * Wq[e * 4 + 0] + t1 * Wq[e * 4 + 1] +
                    t2 * Wq[e * 4 + 2] + t3 * Wq[e * 4 + 3]) * qscale;
            k[e] =  t0 * Wk[e * 4 + 0] + t1 * Wk[e * 4 + 1] +
                    t2 * Wk[e * 4 + 2] + t3 * Wk[e * 4 + 3];
            v[e] =  t0 * Wv[e * 4 + 0] + t1 * Wv[e * 4 + 1] +
                    t2 * Wv[e * 4 + 2] + t3 * Wv[e * 4 + 3];
        }
        const int bh  = b * SH + h;
        const int idx = bh * SS + s;
        qws16[idx] = make_uint2(packh2(q[0], q[1]), packh2(q[2], q[3]));
        kws16[idx] = make_uint2(packh2(k[0], k[1]), packh2(k[2], k[3]));
        #pragma unroll
        for (int e = 0; e < 4; ++e)
            vtg[(bh * 4 + e) * SS + sp] = (_Float16)v[e];   // kappa-permuted
    }
}

// ---------------------------------------------------------------------------
// Kernel 2: MFMA flash attention, two i-blocks per wave, ZERO cross-lane ops
// in the hot loop. The PV B-frags are built directly from the QK C-layout:
//   PV#1 B = cvtpk(regs 0..7)  -> k-order keys [0,1,2,3,8,9,10,11] (lo)
//                                            [4,5,6,7,12,13,14,15] (hi)
//   PV#2 B = cvtpk(regs 8..15) -> same +16
// V^T columns are kappa-pre-permuted (k_ma_qkv) to match, so no
// permlane32_swap is needed (was 8/tile). QK uses mfma_32x32x8_f16 where
// available. l comes free via the ones-row at c=4.
// Grid = B*H * 8 blocks, 4 waves/block, 2 i-blocks/wave.
// ---------------------------------------------------------------------------
#define LDS_K    0
#define LDS_VT   16384
#define VT_STRIDE 4112          // (2048+8) f16 -> breaks bank alignment
#define LDS_Z    36944          // 128 B zero slot (padded-lane reads)
#define LDS_SIZE 37376
#define NT       (SS / 32)      // 64 j-tiles

__global__ __launch_bounds__(256, 2) void k_attn(
    const uint2* __restrict__ qws16,
    const uint2* __restrict__ kws16,
    const unsigned* __restrict__ vtg,   // u32 view of VT f16 [bh][4][SS]
    float4* __restrict__ ows)           // [B*H*S] normalized attention out
{
    __shared__ __align__(16) char lds[LDS_SIZE];

    const int t    = threadIdx.x;
    const int bh   = blockIdx.x >> 3;
    const int part = blockIdx.x & 7;
    const int w    = t >> 6;
    const int ib0  = part * 8 + w;        // first i-block
    const int ib1  = ib0 + 4;             // second i-block
    const int lane = t & 63;
    const int c31  = lane & 31;

    // ---- stage K (16 KB: uint2 per key) ----
    const uint2* kg = kws16 + bh * SS;
    for (int i = t; i < SS; i += 256)
        *(uint2*)(lds + LDS_K + i * 8) = kg[i];
    // ---- stage V^T rows 0..3 (f16, padded row stride; already permuted) ----
    const unsigned* vg = vtg + bh * 4 * (SS / 2);
    for (int i = t; i < 4 * (SS / 2); i += 256) {
        const int cc = i >> 10, col = i & 1023;
        *(unsigned*)(lds + LDS_VT + cc * VT_STRIDE + col * 4) = vg[i];
    }
    // ---- ones row (c = 4) for the l-accumulator ----
    for (int i = t; i < SS / 2; i += 256)
        *(unsigned*)(lds + LDS_VT + 4 * VT_STRIDE + i * 4) = 0x3C003C00u;
    // ---- zero slot ----
    if (t < 32) *(unsigned*)(lds + LDS_Z + t * 4) = 0u;
    __syncthreads();

    // Q B-frags (fixed per wave): lane holds col i=lane&31, k=d (hi lanes 0)
    uint2 qq0 = qws16[bh * SS + ib0 * 32 + c31];
    uint2 qq1 = qws16[bh * SS + ib1 * 32 + c31];
    if (lane >= 32) { qq0.x = 0u; qq0.y = 0u; qq1.x = 0u; qq1.y = 0u; }
    const qkfrag bq0 = make_qk(qq0.x, qq0.y);
    const qkfrag bq1 = make_qk(qq1.x, qq1.y);

    // per-lane LDS addresses (padded lanes read the zero slot, never step)
    int kaddr = (lane < 32) ? (LDS_K + lane * 8) : LDS_Z;
    const int kstep = (lane < 32) ? 256 : 0;            // 32 keys * 8 B
    int vaddr = (c31 < 5) ? (LDS_VT + c31 * VT_STRIDE + (lane >> 5) * 16) : LDS_Z;
    const int vstep = (c31 < 5) ? 64 : 0;               // 32 j * 2 B

    f32x16 oacc0 = {0,0,0,0,0,0,0,0,0,0,0,0,0,0,0,0};
    f32x16 oacc1 = {0,0,0,0,0,0,0,0,0,0,0,0,0,0,0,0};
    const f32x16 zc = {0,0,0,0,0,0,0,0,0,0,0,0,0,0,0,0};

    // ---- prologue: tile 0 scores for both i-blocks in flight ----
    uint2 kk = *(const uint2*)(lds + kaddr); kaddr += kstep;      // K[0]
    f32x16 d0 = qk_mfma(make_qk(kk.x, kk.y), bq0, zc);
    f32x16 d1 = qk_mfma(make_qk(kk.x, kk.y), bq1, zc);
    kk = *(const uint2*)(lds + kaddr); kaddr += kstep;            // K[1]
    uint4 vv0 = *(const uint4*)(lds + vaddr);                     // V[0]
    uint4 vv1 = *(const uint4*)(lds + vaddr + 32); vaddr += vstep;

    for (int jt = 0; jt < NT; ++jt) {
        const qkfrag ak = make_qk(kk.x, kk.y);    // K[jt+1]

        // ---- i-block 0: exp -> reissue QK -> direct-frag PV
        {
            float p[16];
            #pragma unroll
            for (int r = 0; r < 16; ++r) p[r] = fast_exp2(d0[r]);
            d0 = qk_mfma(ak, bq0, zc);            // reissue i0 (tile jt+1)
            const f16x8 av0 = frag4(vv0);
            const f16x8 av1 = frag4(vv1);
            const int pk01 = cvtpk(p[0],  p[1]),  pk23 = cvtpk(p[2],  p[3]);
            const int pk45 = cvtpk(p[4],  p[5]),  pk67 = cvtpk(p[6],  p[7]);
            const int pk89 = cvtpk(p[8],  p[9]),  pkAB = cvtpk(p[10], p[11]);
            const int pkCD = cvtpk(p[12], p[13]), pkEF = cvtpk(p[14], p[15]);
            __builtin_amdgcn_s_setprio(1);
            oacc0 = __builtin_amdgcn_mfma_f32_32x32x16_f16(av0, fragi(pk01, pk23, pk45, pk67), oacc0, 0, 0, 0);
            oacc0 = __builtin_amdgcn_mfma_f32_32x32x16_f16(av1, fragi(pk89, pkAB, pkCD, pkEF), oacc0, 0, 0, 0);
            __builtin_amdgcn_s_setprio(0);
        }

        // ---- i-block 1: exp -> reissue QK -> direct-frag PV
        {
            float p[16];
            #pragma unroll
            for (int r = 0; r < 16; ++r) p[r] = fast_exp2(d1[r]);
            d1 = qk_mfma(ak, bq1, zc);            // reissue i1 (tile jt+1)
            const f16x8 av0 = frag4(vv0);
            const f16x8 av1 = frag4(vv1);
            // advance K/V streams for the next tile
            kk  = *(const uint2*)(lds + kaddr); kaddr += kstep;   // K[jt+2]
            vv0 = *(const uint4*)(lds + vaddr);                   // V[jt+1]
            vv1 = *(const uint4*)(lds + vaddr + 32); vaddr += vstep;
            const int pk01 = cvtpk(p[0],  p[1]),  pk23 = cvtpk(p[2],  p[3]);
            const int pk45 = cvtpk(p[4],  p[5]),  pk67 = cvtpk(p[6],  p[7]);
            const int pk89 = cvtpk(p[8],  p[9]),  pkAB = cvtpk(p[10], p[11]);
            const int pkCD = cvtpk(p[12], p[13]), pkEF = cvtpk(p[14], p[15]);
            __builtin_amdgcn_s_setprio(1);
            oacc1 = __builtin_amdgcn_mfma_f32_32x32x16_f16(av0, fragi(pk01, pk23, pk45, pk67), oacc1, 0, 0, 0);
            oacc1 = __builtin_amdgcn_mfma_f32_32x32x16_f16(av1, fragi(pk89, pkAB, pkCD, pkEF), oacc1, 0, 0, 0);
            __builtin_amdgcn_s_setprio(0);
        }
    }

    // l sits in reg0 of lanes>=32 (row c=4); bring to lanes<32 and normalize.
    {
        union { float f; int i; } u0; u0.f = oacc0[0];
        int s0i, s1i;
        swap32(u0.i, u0.i, lane, s0i, s1i);
        union { int i; float f; } ul; ul.i = s1i;
        if (lane < 32) {
            const float inv = 1.0f / ul.f;
            ows[bh * SS + ib0 * 32 + lane] =
                make_float4(oacc0[0] * inv, oacc0[1] * inv, oacc0[2] * inv, oacc0[3] * inv);
        }
    }
    {
        union { float f; int i; } u0; u0.f = oacc1[0];
        int s0i, s1i;
        swap32(u0.i, u0.i, lane, s0i, s1i);
        union { int i; float f; } ul; ul.i = s1i;
        if (lane < 32) {
            const float inv = 1.0f / ul.f;
            ows[bh * SS + ib1 * 32 + lane] =
                make_float4(oacc1[0] * inv, oacc1[1] * inv, oacc1[2] * inv, oacc1[3] * inv);
        }
    }
}

// ---------------------------------------------------------------------------
// Kernel 3: epilogue (unchanged). O already normalized.
// ---------------------------------------------------------------------------
__global__ __launch_bounds__(256) void k_epilogue(
    const float* __restrict__ x,      // [B,S]
    const float* __restrict__ Wo,     // [8,8]
    const float* __restrict__ bo,     // [8]
    const float4* __restrict__ ows,
    const float4* __restrict__ mmws,
    float* __restrict__ out)          // seasonal [B*S] then trend [B*S]
{
    const int pos = blockIdx.x * 256 + threadIdx.x;  // = b*S + s
    const int b = pos / SS;
    const int s = pos % SS;

    const float4 o0 = ows[(b * SH + 0) * SS + s];
    const float4 o1 = ows[(b * SH + 1) * SS + s];
    const float ov[8] = {o0.x, o0.y, o0.z, o0.w, o1.x, o1.y, o1.z, o1.w};

    float g[8];
    float m = -1e30f;
    #pragma unroll
    for (int e = 0; e < 8; ++e) {
        float acc = bo[e];
        #pragma unroll
        for (int f = 0; f < 8; ++f) acc += ov[f] * Wo[e * 8 + f];
        g[e] = acc;
        m = fmaxf(m, acc);
    }
    float l = 0.0f;
    #pragma unroll
    for (int e = 0; e < 8; ++e) { g[e] = __expf(g[e] - m); l += g[e]; }
    const float inv = 1.0f / l;

    const float4 mm0 = mmws[pos * 2 + 0];
    const float4 mm1 = mmws[pos * 2 + 1];
    const float mv[8] = {mm0.x, mm0.y, mm0.z, mm0.w, mm1.x, mm1.y, mm1.z, mm1.w};

    float trend = 0.0f;
    #pragma unroll
    for (int e = 0; e < 8; ++e) trend += g[e] * inv * mv[e];

    out[pos]           = x[pos] - trend;   // seasonal
    out[SB * SS + pos] = trend;            // trend
}

extern "C" void kernel_launch(void* const* d_in, const int* in_sizes, int n_in,
                              void* d_out, int out_size, void* d_ws, size_t ws_size,
                              hipStream_t stream) {
    const float* x  = (const float*)d_in[0];
    const float* Wq = (const float*)d_in[1];
    const float* Wk = (const float*)d_in[2];
    const float* Wv = (const float*)d_in[3];
    const float* Wo = (const float*)d_in[4];
    const float* bo = (const float*)d_in[5];

    uint2*     qws16 = (uint2*)d_ws;                        // 1 MB
    uint2*     kws16 = qws16 + SB * SH * SS;                // 1 MB
    _Float16*  vtg   = (_Float16*)(kws16 + SB * SH * SS);   // 1 MB  [bh][4][S]
    float4*    mmws  = (float4*)(vtg + SB * SH * 4 * SS);   // 2 MB
    float4*    ows   = mmws + SB * SS * 2;                  // 2 MB

    k_ma_qkv<<<SB * (SS / 256), 256, 0, stream>>>(x, Wq, Wk, Wv, qws16, kws16, vtg, mmws);
    k_attn<<<SB * SH * 8, 256, 0, stream>>>(qws16, kws16, (const unsigned*)vtg, ows);
    k_epilogue<<<(SB * SS) / 256, 256, 0, stream>>>(x, Wo, bo, ows, mmws, (float*)d_out);
}